// Round 6
// baseline (430.069 us; speedup 1.0000x reference)
//
#include <hip/hip_runtime.h>
#include <hip/hip_bf16.h>
#include <stdint.h>

#define B_    8
#define S_    4096
#define D_    1536
#define ORG_  4
#define OUT_  2048

typedef __bf16 bf16;
typedef __attribute__((ext_vector_type(8)))  bf16  bf16x8;
typedef __attribute__((ext_vector_type(16))) float f32x16;

#define BK64 64
#define NKT  (D_ / BK64)   // 24 K-tiles

// ------ convert + transpose w: f32 [ORG][D][OUT] -> bf16 [ORG][OUT][D] ------
__global__ void k_cvt_wT(const float* __restrict__ w, bf16* __restrict__ wt) {
  __shared__ float tile[32][33];
  int org = blockIdx.z;
  int n0 = blockIdx.x * 32;   // OUT dim
  int d0 = blockIdx.y * 32;   // D dim
  const float* wsrc = w + (size_t)org * D_ * OUT_;
  bf16* wdst = wt + (size_t)org * OUT_ * D_;
  int tx = threadIdx.x, ty = threadIdx.y;
#pragma unroll
  for (int j = 0; j < 32; j += 8)
    tile[ty + j][tx] = wsrc[(size_t)(d0 + ty + j) * OUT_ + (n0 + tx)];
  __syncthreads();
#pragma unroll
  for (int j = 0; j < 32; j += 8)
    wdst[(size_t)(n0 + ty + j) * D_ + (d0 + tx)] = (bf16)tile[tx][ty + j];
}

// ----- 256x256 8-phase 32x32x16 bf16 MFMA GEMM with fused f32->bf16 A-stage -
// A = x[batch] : [S][D] f32 (converted in-kernel during staging)
// B = wt[org]  : [OUT][D] bf16 row-major (B^T form)
// C[m][n] = sum_k A[m][k]*B[n][k] + bias[n]
// LDS swizzle key(r) = (r&7) ^ ((r>>3)&3) (both-sides; conflict-free for the
// 32x32 fragment's row=lane&31 ds_read_b128, verified round 5).
__global__ __launch_bounds__(512, 2)
void k_gemm256(const float* __restrict__ x, const bf16* __restrict__ wt,
               const int* __restrict__ oidx, const float* __restrict__ bias,
               float* __restrict__ out) {
  __shared__ __align__(16) char smem[131072];   // A: 2x32KB, B: 2x32KB
  char* const ldsA = smem;
  char* const ldsB = smem + 65536;

  const int batch = blockIdx.y;
  const int bx = blockIdx.x;
  // T1: XCD-aware swizzle (128 tiles, 8 XCDs). XCD = bx&7 owns one tn column.
  const int swz = (bx & 7) * 16 + (bx >> 3);
  const int tn = swz >> 4, tm = swz & 15;
  const int m0 = tm * 256, n0 = tn * 256;
  const int org = oidx[batch];

  const float* Af = x  + (size_t)batch * S_ * D_ + (size_t)m0 * D_;     // f32 A
  const bf16*  Bg = wt + (size_t)org * OUT_ * D_ + (size_t)n0 * D_;

  const int tid  = threadIdx.x;
  const int lane = tid & 63, wv = tid >> 6;
  const int wr = wv >> 2, wc = wv & 3;        // 2x4 wave grid, per-wave 128x64 out
  const int l31 = lane & 31, hi = lane >> 5;

  // Read-side swizzle (reduces to lane expr for both A and B row bases)
  const int xorv = ((lane & 7) ^ ((lane >> 3) & 3)) << 4;
  const int off[4] = { (0  + hi * 16) ^ xorv, (32 + hi * 16) ^ xorv,
                       (64 + hi * 16) ^ xorv, (96 + hi * 16) ^ xorv };
  const int arow = (wr * 128 + l31) * 128;    // + mt*4096
  const int brow = (wc * 64  + l31) * 128;    // + nt*4096

  // B stage-side (gload_lds): linear LDS dest + inverse-swizzled global source
  const int srow = tid >> 3;
  const int scol = (((tid & 7) ^ ((tid >> 3) & 7) ^ ((tid >> 6) & 3))) << 3;
  const int soff = wv * 1024;

  // A stage-side (reg path): thread owns row s_arow of each 128-row half,
  // chunk-pair cb0 = 16 f32 (64B contiguous) -> 2 swizzled ds_write_b128.
  const int s_arow = tid >> 2;                // 0..127
  const int cb0    = (tid & 3) * 2;           // chunk pair base (8 bf16/chunk)
  const int s_acol = cb0 * 8;                 // f32 elems
  const int akey   = (s_arow & 7) ^ ((s_arow >> 3) & 3);

#define LDA(v, mt, ks) (*(const bf16x8*)(ldsA + (v)*32768 + arow + (mt)*4096 + off[ks]))
#define LDB(v, nt, ks) (*(const bf16x8*)(ldsB + (v)*32768 + brow + (nt)*4096 + off[ks]))

#define STAGE_B(h, kb, vbase) do {                                                       \
    __builtin_amdgcn_global_load_lds(                                                    \
      (__attribute__((address_space(1))) void*)(Bg + (size_t)((h)*128 + srow) * D_ + (kb) + scol), \
      (__attribute__((address_space(3))) void*)((vbase) + (h)*16384 + soff), 16, 0, 0);  \
    __builtin_amdgcn_global_load_lds(                                                    \
      (__attribute__((address_space(1))) void*)(Bg + (size_t)((h)*128 + 64 + srow) * D_ + (kb) + scol), \
      (__attribute__((address_space(3))) void*)((vbase) + (h)*16384 + 8192 + soff), 16, 0, 0); \
  } while (0)

  // Issue 4 global_load_dwordx4 (f32) for one 128-row A-half into registers.
#define A_LOAD(la, h, kb) do {                                                           \
    const float* s_ = Af + (size_t)((h)*128 + s_arow) * D_ + (kb) + s_acol;              \
    la[0] = *(const float4*)(s_);      la[1] = *(const float4*)(s_ + 4);                 \
    la[2] = *(const float4*)(s_ + 8);  la[3] = *(const float4*)(s_ + 12);                \
  } while (0)

#define CVT8(dst, f0, f1) do {                                                           \
    dst[0]=(bf16)(f0).x; dst[1]=(bf16)(f0).y; dst[2]=(bf16)(f0).z; dst[3]=(bf16)(f0).w;  \
    dst[4]=(bf16)(f1).x; dst[5]=(bf16)(f1).y; dst[6]=(bf16)(f1).z; dst[7]=(bf16)(f1).w;  \
  } while (0)

  // Convert both held A-halves and ds_write_b128 with direct write-side swizzle.
#define WRITE_A2(vbase) do {                                                             \
    bf16x8 v_;                                                                           \
    CVT8(v_, la0[0], la0[1]);                                                            \
    *(bf16x8*)((vbase) + s_arow*128 + ((cb0 ^ akey) << 4)) = v_;                         \
    CVT8(v_, la0[2], la0[3]);                                                            \
    *(bf16x8*)((vbase) + s_arow*128 + (((cb0 + 1) ^ akey) << 4)) = v_;                   \
    CVT8(v_, la1[0], la1[1]);                                                            \
    *(bf16x8*)((vbase) + 16384 + s_arow*128 + ((cb0 ^ akey) << 4)) = v_;                 \
    CVT8(v_, la1[2], la1[3]);                                                            \
    *(bf16x8*)((vbase) + 16384 + s_arow*128 + (((cb0 + 1) ^ akey) << 4)) = v_;           \
  } while (0)

#define SBAR()  __builtin_amdgcn_s_barrier()
#define LGK0()  asm volatile("s_waitcnt lgkmcnt(0)" ::: "memory")
#define VMC4()  asm volatile("s_waitcnt vmcnt(4)" ::: "memory")
#define VMC0()  asm volatile("s_waitcnt vmcnt(0)" ::: "memory")
#define PRIO(p) __builtin_amdgcn_s_setprio(p)

  float4 la0[4], la1[4];
  bf16x8 a[2][4], b0[4], b1[4];
  f32x16 acc[4][2];
#pragma unroll
  for (int mt = 0; mt < 4; ++mt)
#pragma unroll
    for (int nt = 0; nt < 2; ++nt)
#pragma unroll
      for (int rr = 0; rr < 16; ++rr) acc[mt][nt][rr] = 0.f;

#define READ_A2(v, mbase) do { _Pragma("unroll") for (int mm = 0; mm < 2; ++mm) \
    _Pragma("unroll") for (int ks = 0; ks < 4; ++ks) \
      a[mm][ks] = LDA(v, (mbase) + mm, ks); } while (0)
#define READ_B4(v, nt, bb) do { _Pragma("unroll") for (int ks = 0; ks < 4; ++ks) \
      bb[ks] = LDB(v, nt, ks); } while (0)
#define MFMA_O(mbase, nt, bb) do { \
    _Pragma("unroll") for (int mm = 0; mm < 2; ++mm) \
    _Pragma("unroll") for (int ks = 0; ks < 4; ++ks) \
      acc[(mbase)+mm][nt] = __builtin_amdgcn_mfma_f32_32x32x16_bf16( \
          a[mm][ks], bb[ks], acc[(mbase)+mm][nt], 0, 0, 0); } while (0)

  // ---- prologue: B(0) gload, A(0) f32->regs, B(1) gload; vmcnt(4) waits
  // oldest-12 = B(0)+A(0); convert+write A(0) -> buf0; B(1) stays in flight.
  STAGE_B(0, 0, ldsB);
  STAGE_B(1, 0, ldsB);
  A_LOAD(la0, 0, 0);
  A_LOAD(la1, 1, 0);
  STAGE_B(0, BK64, ldsB + 32768);
  STAGE_B(1, BK64, ldsB + 32768);
  VMC4();
  WRITE_A2(ldsA);
  LGK0();
  SBAR();

  for (int i = 0; i < NKT / 2; ++i) {
    const int k1 = (2 * i + 1) * BK64;
    int t2 = 2 * i + 2; if (t2 > NKT - 1) t2 = NKT - 1;   // clamp, never skip:
    int t3 = 2 * i + 3; if (t3 > NKT - 1) t3 = NKT - 1;   // keeps vmcnt math exact
    const int k2 = t2 * BK64, k3 = t3 * BK64;

    // P1: tile 2i quad(mt0-1 x nt0); issue A-half0(2i+1) f32 loads
    READ_A2(0, 0); READ_B4(0, 0, b0);
    A_LOAD(la0, 0, k1);
    SBAR(); LGK0();
    PRIO(1); MFMA_O(0, 0, b0); PRIO(0);
    SBAR();
    // P2: quad(mt0-1 x nt1); issue A-half1(2i+1) f32 loads
    READ_B4(0, 1, b1);
    A_LOAD(la1, 1, k1);
    SBAR(); LGK0();
    PRIO(1); MFMA_O(0, 1, b1); PRIO(0);
    SBAR();
    // P3: quad(mt2-3 x nt0); stage B-half0(2i+2) -> buf0
    READ_A2(0, 2);
    STAGE_B(0, k2, ldsB);
    SBAR(); LGK0();
    PRIO(1); MFMA_O(2, 0, b0); PRIO(0);
    SBAR();
    // P4: quad(mt2-3 x nt1); stage B-half1(2i+2); vmcnt(4) -> A(2i+1) regs
    // ready; convert+write A(2i+1) -> buf1; drain ds_writes before barrier.
    STAGE_B(1, k2, ldsB);
    SBAR();
    VMC4();
    WRITE_A2(ldsA + 32768);
    PRIO(1); MFMA_O(2, 1, b1); PRIO(0);
    LGK0();
    SBAR();
    // P5: tile 2i+1 quad(mt0-1 x nt0); issue A-half0(2i+2) f32 loads
    READ_A2(1, 0); READ_B4(1, 0, b0);
    A_LOAD(la0, 0, k2);
    SBAR(); LGK0();
    PRIO(1); MFMA_O(0, 0, b0); PRIO(0);
    SBAR();
    // P6: quad(mt0-1 x nt1); issue A-half1(2i+2) f32 loads
    READ_B4(1, 1, b1);
    A_LOAD(la1, 1, k2);
    SBAR(); LGK0();
    PRIO(1); MFMA_O(0, 1, b1); PRIO(0);
    SBAR();
    // P7: quad(mt2-3 x nt0); stage B-half0(2i+3) -> buf1
    READ_A2(1, 2);
    STAGE_B(0, k3, ldsB + 32768);
    SBAR(); LGK0();
    PRIO(1); MFMA_O(2, 0, b0); PRIO(0);
    SBAR();
    // P8: quad(mt2-3 x nt1); stage B-half1(2i+3); vmcnt(4) -> B(2i+2)+A(2i+2)
    // complete; convert+write A(2i+2) -> buf0.
    STAGE_B(1, k3, ldsB + 32768);
    SBAR();
    VMC4();
    WRITE_A2(ldsA);
    PRIO(1); MFMA_O(2, 1, b1); PRIO(0);
    LGK0();
    SBAR();
  }

  VMC0();  // drain trailing (clamped) B stages before stores

  // epilogue: 32x32 C/D layout col = lane&31, row = (reg&3)+8*(reg>>2)+4*(lane>>5)
  float* Og = out + (size_t)batch * S_ * OUT_ + (size_t)m0 * OUT_ + n0;
  const float* bbase = bias + (size_t)org * OUT_ + n0;
#pragma unroll
  for (int nt = 0; nt < 2; ++nt) {
    const int col = wc * 64 + nt * 32 + l31;
    const float bv = bbase[col];
#pragma unroll
    for (int mt = 0; mt < 4; ++mt) {
#pragma unroll
      for (int rr = 0; rr < 16; ++rr) {
        const int row = wr * 128 + mt * 32 + 4 * hi + (rr & 3) + 8 * (rr >> 2);
        Og[(size_t)row * OUT_ + col] = acc[mt][nt][rr] + bv;
      }
    }
  }
#undef LDA
#undef LDB
#undef STAGE_B
#undef A_LOAD
#undef CVT8
#undef WRITE_A2
#undef SBAR
#undef LGK0
#undef VMC4
#undef VMC0
#undef PRIO
#undef READ_A2
#undef READ_B4
#undef MFMA_O
}

// ---------------- fallback: naive fp32 (only if ws too small) ---------------
__global__ void k_gemm_fallback(const float* __restrict__ x, const int* __restrict__ oidx,
                                const float* __restrict__ w, const float* __restrict__ bias,
                                float* __restrict__ out) {
  const int b = blockIdx.z;
  const int org = oidx[b];
  const int n = blockIdx.x * 64 + threadIdx.x;
  const int m = blockIdx.y * 4 + threadIdx.y;
  const float* xr = x + ((size_t)b * S_ + m) * D_;
  const float* wp = w + (size_t)org * D_ * OUT_ + n;
  float acc = 0.f;
  for (int k = 0; k < D_; ++k) acc += xr[k] * wp[(size_t)k * OUT_];
  out[((size_t)b * S_ + m) * OUT_ + n] = acc + bias[(size_t)org * OUT_ + n];
}

extern "C" void kernel_launch(void* const* d_in, const int* in_sizes, int n_in,
                              void* d_out, int out_size, void* d_ws, size_t ws_size,
                              hipStream_t stream) {
  const float* x    = (const float*)d_in[0];
  const int*   oidx = (const int*)d_in[1];
  const float* w    = (const float*)d_in[2];
  const float* bias = (const float*)d_in[3];
  float* out = (float*)d_out;

  const size_t wt_elems = (size_t)ORG_ * OUT_ * D_;  // 12,582,912
  const size_t need = wt_elems * sizeof(bf16);       // ~25 MB

  if (ws_size < need) {
    dim3 g(OUT_ / 64, S_ / 4, B_);
    k_gemm_fallback<<<g, dim3(64, 4), 0, stream>>>(x, oidx, w, bias, out);
    return;
  }

  bf16* wt = (bf16*)d_ws;

  dim3 gt(OUT_ / 32, D_ / 32, ORG_);
  k_cvt_wT<<<gt, dim3(32, 8), 0, stream>>>(w, wt);
  dim3 gg(128, B_);
  k_gemm256<<<gg, 512, 0, stream>>>(x, wt, oidx, bias, out);
}

// Round 7
// 301.008 us; speedup vs baseline: 1.4288x; 1.4288x over previous
//
#include <hip/hip_runtime.h>
#include <hip/hip_bf16.h>
#include <stdint.h>

#define B_    8
#define S_    4096
#define D_    1536
#define ORG_  4
#define OUT_  2048

typedef __bf16 bf16;
typedef __attribute__((ext_vector_type(8)))  bf16  bf16x8;
typedef __attribute__((ext_vector_type(16))) float f32x16;

#define BK64 64
#define NKT  (D_ / BK64)   // 24 K-tiles

#define XBLKS 2048                       // blocks doing the x-stream part
#define WTBLK (ORG_ * (OUT_/32) * (D_/32))  // 12288 blocks doing w-transpose

// ---- merged convert: x f32->bf16 stream  +  w f32 [O][D][OUT] -> bf16 [O][OUT][D]
__global__ void k_cvt_all(const float* __restrict__ x, bf16* __restrict__ xb,
                          const float* __restrict__ w, bf16* __restrict__ wt) {
  __shared__ float tile[32][33];
  const int bx = blockIdx.x;
  const int tid = threadIdx.x;

  if (bx < XBLKS) {
    // -------- x part: 8 elems/thread/iter, grid-stride --------
    const long n8 = (long)B_ * S_ * D_ / 8;   // 6,291,456
    long i = (long)bx * blockDim.x + tid;
    const long stride = (long)XBLKS * blockDim.x;
    for (; i < n8; i += stride) {
      const float4* p = (const float4*)(x + i * 8);
      float4 a = p[0];
      float4 b = p[1];
      bf16x8 v;
      v[0] = (bf16)a.x; v[1] = (bf16)a.y; v[2] = (bf16)a.z; v[3] = (bf16)a.w;
      v[4] = (bf16)b.x; v[5] = (bf16)b.y; v[6] = (bf16)b.z; v[7] = (bf16)b.w;
      *(bf16x8*)(xb + i * 8) = v;
    }
  } else {
    // -------- w part: 32x32 tile transpose --------
    const int q   = bx - XBLKS;
    const int org = q / ((OUT_/32) * (D_/32));
    const int rem = q % ((OUT_/32) * (D_/32));
    const int d0  = (rem / (OUT_/32)) * 32;
    const int n0  = (rem % (OUT_/32)) * 32;
    const int tx = tid & 31, ty = tid >> 5;   // 32 x 8
    const float* wsrc = w + (size_t)org * D_ * OUT_;
    bf16* wdst = wt + (size_t)org * OUT_ * D_;
#pragma unroll
    for (int j = 0; j < 32; j += 8)
      tile[ty + j][tx] = wsrc[(size_t)(d0 + ty + j) * OUT_ + (n0 + tx)];
    __syncthreads();
#pragma unroll
    for (int j = 0; j < 32; j += 8)
      wdst[(size_t)(n0 + ty + j) * D_ + (d0 + tx)] = (bf16)tile[tx][ty + j];
  }
}

// ----- 256x256 8-phase bf16 MFMA GEMM, 32x32x16 shape (T1+T2+T3+T4+T5) ------
// A = xb[batch] : [S][D] row-major;  B = wt[org] : [OUT][D] row-major (B^T)
// C[m][n] = sum_k A[m][k]*B[n][k]  + bias[n]
// LDS swizzle key(r) = (r&7) ^ ((r>>3)&3), both-sides (verified round 5: 0
// bank conflicts). Schedule byte-identical to round 5 except the optional
// lgkmcnt(8) pre-barrier hint in the two 12-ds_read phases (P1/P5).
__global__ __launch_bounds__(512, 2)
void k_gemm256(const bf16* __restrict__ xb, const bf16* __restrict__ wt,
               const int* __restrict__ oidx, const float* __restrict__ bias,
               float* __restrict__ out) {
  __shared__ __align__(16) char smem[131072];   // A: 2x32KB, B: 2x32KB
  char* const ldsA = smem;
  char* const ldsB = smem + 65536;

  const int batch = blockIdx.y;
  const int bx = blockIdx.x;
  // T1: XCD-aware swizzle (128 tiles, 8 XCDs). XCD = bx&7 owns one tn column.
  const int swz = (bx & 7) * 16 + (bx >> 3);
  const int tn = swz >> 4, tm = swz & 15;
  const int m0 = tm * 256, n0 = tn * 256;
  const int org = oidx[batch];

  const bf16* Ag = xb + (size_t)batch * S_ * D_ + (size_t)m0 * D_;
  const bf16* Bg = wt + (size_t)org * OUT_ * D_ + (size_t)n0 * D_;

  const int tid  = threadIdx.x;
  const int lane = tid & 63, wv = tid >> 6;
  const int wr = wv >> 2, wc = wv & 3;        // 2x4 wave grid, per-wave 128x64 out
  const int l31 = lane & 31, hi = lane >> 5;

  // Read-side swizzle: key(row) reduces to lane expr for both A and B bases.
  const int xorv = ((lane & 7) ^ ((lane >> 3) & 3)) << 4;
  const int off[4] = { (0  + hi * 16) ^ xorv, (32 + hi * 16) ^ xorv,
                       (64 + hi * 16) ^ xorv, (96 + hi * 16) ^ xorv };
  const int arow = (wr * 128 + l31) * 128;    // + mt*4096
  const int brow = (wc * 64  + l31) * 128;    // + nt*4096

  // Stage-side: linear LDS dest + inverse-swizzled per-lane GLOBAL source.
  const int srow = tid >> 3;
  const int scol = (((tid & 7) ^ ((tid >> 3) & 7) ^ ((tid >> 6) & 3))) << 3;
  const int soff = wv * 1024;

#define LDA(v, mt, ks) (*(const bf16x8*)(ldsA + (v)*32768 + arow + (mt)*4096 + off[ks]))
#define LDB(v, nt, ks) (*(const bf16x8*)(ldsB + (v)*32768 + brow + (nt)*4096 + off[ks]))

#define STAGE_HALF(gptr, ldsbase, h, kb) do {                                            \
    __builtin_amdgcn_global_load_lds(                                                    \
      (__attribute__((address_space(1))) void*)((gptr) + (size_t)((h)*128 + srow) * D_ + (kb) + scol), \
      (__attribute__((address_space(3))) void*)((ldsbase) + (h)*16384 + soff), 16, 0, 0);\
    __builtin_amdgcn_global_load_lds(                                                    \
      (__attribute__((address_space(1))) void*)((gptr) + (size_t)((h)*128 + 64 + srow) * D_ + (kb) + scol), \
      (__attribute__((address_space(3))) void*)((ldsbase) + (h)*16384 + 8192 + soff), 16, 0, 0); \
  } while (0)

#define SBAR()  __builtin_amdgcn_s_barrier()
#define LGK0()  asm volatile("s_waitcnt lgkmcnt(0)" ::: "memory")
#define LGK8()  asm volatile("s_waitcnt lgkmcnt(8)" ::: "memory")
#define VMC4()  asm volatile("s_waitcnt vmcnt(4)" ::: "memory")
#define VMC0()  asm volatile("s_waitcnt vmcnt(0)" ::: "memory")
#define PRIO(p) __builtin_amdgcn_s_setprio(p)

  bf16x8 a[2][4], b0[4], b1[4];
  f32x16 acc[4][2];
#pragma unroll
  for (int mt = 0; mt < 4; ++mt)
#pragma unroll
    for (int nt = 0; nt < 2; ++nt)
#pragma unroll
      for (int rr = 0; rr < 16; ++rr) acc[mt][nt][rr] = 0.f;

#define READ_A2(v, mbase) do { _Pragma("unroll") for (int mm = 0; mm < 2; ++mm) \
    _Pragma("unroll") for (int ks = 0; ks < 4; ++ks) \
      a[mm][ks] = LDA(v, (mbase) + mm, ks); } while (0)
#define READ_B4(v, nt, bb) do { _Pragma("unroll") for (int ks = 0; ks < 4; ++ks) \
      bb[ks] = LDB(v, nt, ks); } while (0)
#define MFMA_O(mbase, nt, bb) do { \
    _Pragma("unroll") for (int mm = 0; mm < 2; ++mm) \
    _Pragma("unroll") for (int ks = 0; ks < 4; ++ks) \
      acc[(mbase)+mm][nt] = __builtin_amdgcn_mfma_f32_32x32x16_bf16( \
          a[mm][ks], bb[ks], acc[(mbase)+mm][nt], 0, 0, 0); } while (0)

  // ---- prologue: tile0 B+A, tile1 B (6 halves = 12 loads); newest 2 halves
  // (tile1 B) may stay outstanding at the barrier.
  STAGE_HALF(Bg, ldsB, 0, 0);
  STAGE_HALF(Bg, ldsB, 1, 0);
  STAGE_HALF(Ag, ldsA, 0, 0);
  STAGE_HALF(Ag, ldsA, 1, 0);
  STAGE_HALF(Bg, ldsB + 32768, 0, BK64);
  STAGE_HALF(Bg, ldsB + 32768, 1, BK64);
  VMC4();
  SBAR();

  for (int i = 0; i < NKT / 2; ++i) {
    const int k1 = (2 * i + 1) * BK64;
    int t2 = 2 * i + 2; if (t2 > NKT - 1) t2 = NKT - 1;   // clamp, never skip:
    int t3 = 2 * i + 3; if (t3 > NKT - 1) t3 = NKT - 1;   // keeps vmcnt math exact
    const int k2 = t2 * BK64, k3 = t3 * BK64;

    // P1: tile 2i, quad(mt0-1 x nt0); stage A-half0(2i+1) -> buf1
    READ_A2(0, 0); READ_B4(0, 0, b0);
    STAGE_HALF(Ag, ldsA + 32768, 0, k1);
    LGK8();
    SBAR(); LGK0();
    PRIO(1); MFMA_O(0, 0, b0); PRIO(0);
    SBAR();
    // P2: quad(mt0-1 x nt1); stage A-half1(2i+1) -> buf1
    READ_B4(0, 1, b1);
    STAGE_HALF(Ag, ldsA + 32768, 1, k1);
    SBAR(); LGK0();
    PRIO(1); MFMA_O(0, 1, b1); PRIO(0);
    SBAR();
    // P3: quad(mt2-3 x nt0); stage B-half0(2i+2) -> buf0
    READ_A2(0, 2);
    STAGE_HALF(Bg, ldsB, 0, k2);
    SBAR(); LGK0();
    PRIO(1); MFMA_O(2, 0, b0); PRIO(0);
    SBAR();
    // P4: quad(mt2-3 x nt1); stage B-half1(2i+2); checkpoint vmcnt(4)
    STAGE_HALF(Bg, ldsB, 1, k2);
    SBAR();
    PRIO(1); MFMA_O(2, 1, b1); PRIO(0);
    VMC4();
    SBAR();
    // P5: tile 2i+1, quad(mt0-1 x nt0); stage A-half0(2i+2) -> buf0
    READ_A2(1, 0); READ_B4(1, 0, b0);
    STAGE_HALF(Ag, ldsA, 0, k2);
    LGK8();
    SBAR(); LGK0();
    PRIO(1); MFMA_O(0, 0, b0); PRIO(0);
    SBAR();
    // P6: quad(mt0-1 x nt1); stage A-half1(2i+2) -> buf0
    READ_B4(1, 1, b1);
    STAGE_HALF(Ag, ldsA, 1, k2);
    SBAR(); LGK0();
    PRIO(1); MFMA_O(0, 1, b1); PRIO(0);
    SBAR();
    // P7: quad(mt2-3 x nt0); stage B-half0(2i+3) -> buf1
    READ_A2(1, 2);
    STAGE_HALF(Bg, ldsB + 32768, 0, k3);
    SBAR(); LGK0();
    PRIO(1); MFMA_O(2, 0, b0); PRIO(0);
    SBAR();
    // P8: quad(mt2-3 x nt1); stage B-half1(2i+3); checkpoint vmcnt(4)
    STAGE_HALF(Bg, ldsB + 32768, 1, k3);
    SBAR();
    PRIO(1); MFMA_O(2, 1, b1); PRIO(0);
    VMC4();
    SBAR();
  }

  VMC0();  // drain trailing (clamped) stages before stores

  // epilogue: 32x32 C/D layout col = lane&31, row = (reg&3)+8*(reg>>2)+4*(lane>>5)
  float* Og = out + (size_t)batch * S_ * OUT_ + (size_t)m0 * OUT_ + n0;
  const float* bbase = bias + (size_t)org * OUT_ + n0;
#pragma unroll
  for (int nt = 0; nt < 2; ++nt) {
    const int col = wc * 64 + nt * 32 + l31;
    const float bv = bbase[col];
#pragma unroll
    for (int mt = 0; mt < 4; ++mt) {
#pragma unroll
      for (int rr = 0; rr < 16; ++rr) {
        const int row = wr * 128 + mt * 32 + 4 * hi + (rr & 3) + 8 * (rr >> 2);
        Og[(size_t)row * OUT_ + col] = acc[mt][nt][rr] + bv;
      }
    }
  }
#undef LDA
#undef LDB
#undef STAGE_HALF
#undef SBAR
#undef LGK0
#undef LGK8
#undef VMC4
#undef VMC0
#undef PRIO
#undef READ_A2
#undef READ_B4
#undef MFMA_O
}

// ---------------- fallback: naive fp32 (only if ws too small) ---------------
__global__ void k_gemm_fallback(const float* __restrict__ x, const int* __restrict__ oidx,
                                const float* __restrict__ w, const float* __restrict__ bias,
                                float* __restrict__ out) {
  const int b = blockIdx.z;
  const int org = oidx[b];
  const int n = blockIdx.x * 64 + threadIdx.x;
  const int m = blockIdx.y * 4 + threadIdx.y;
  const float* xr = x + ((size_t)b * S_ + m) * D_;
  const float* wp = w + (size_t)org * D_ * OUT_ + n;
  float acc = 0.f;
  for (int k = 0; k < D_; ++k) acc += xr[k] * wp[(size_t)k * OUT_];
  out[((size_t)b * S_ + m) * OUT_ + n] = acc + bias[(size_t)org * OUT_ + n];
}

extern "C" void kernel_launch(void* const* d_in, const int* in_sizes, int n_in,
                              void* d_out, int out_size, void* d_ws, size_t ws_size,
                              hipStream_t stream) {
  const float* x    = (const float*)d_in[0];
  const int*   oidx = (const int*)d_in[1];
  const float* w    = (const float*)d_in[2];
  const float* bias = (const float*)d_in[3];
  float* out = (float*)d_out;

  const size_t xb_elems = (size_t)B_ * S_ * D_;      // 50,331,648
  const size_t wt_elems = (size_t)ORG_ * OUT_ * D_;  // 12,582,912
  const size_t need = (xb_elems + wt_elems) * sizeof(bf16);  // ~126 MB

  if (ws_size < need) {
    dim3 g(OUT_ / 64, S_ / 4, B_);
    k_gemm_fallback<<<g, dim3(64, 4), 0, stream>>>(x, oidx, w, bias, out);
    return;
  }

  bf16* xb = (bf16*)d_ws;
  bf16* wt = xb + xb_elems;

  k_cvt_all<<<XBLKS + WTBLK, 256, 0, stream>>>(x, xb, w, wt);
  dim3 gg(128, B_);
  k_gemm256<<<gg, 512, 0, stream>>>(xb, wt, oidx, bias, out);
}

// Round 8
// 296.097 us; speedup vs baseline: 1.4525x; 1.0166x over previous
//
#include <hip/hip_runtime.h>
#include <hip/hip_bf16.h>
#include <stdint.h>

#define B_    8
#define S_    4096
#define D_    1536
#define ORG_  4
#define OUT_  2048

typedef __bf16 bf16;
typedef __attribute__((ext_vector_type(8)))  bf16  bf16x8;
typedef __attribute__((ext_vector_type(16))) float f32x16;

#define BK64 64
#define NKT  (D_ / BK64)   // 24 K-tiles

#define XBLKS 2048                       // blocks doing the x-stream part
#define WTBLK (ORG_ * (OUT_/32) * (D_/32))  // 12288 blocks doing w-transpose

// ---- merged convert: x f32->bf16 stream  +  w f32 [O][D][OUT] -> bf16 [O][OUT][D]
__global__ void k_cvt_all(const float* __restrict__ x, bf16* __restrict__ xb,
                          const float* __restrict__ w, bf16* __restrict__ wt) {
  __shared__ float tile[32][33];
  const int bx = blockIdx.x;
  const int tid = threadIdx.x;

  if (bx < XBLKS) {
    // -------- x part: 8 elems/thread/iter, grid-stride --------
    const long n8 = (long)B_ * S_ * D_ / 8;   // 6,291,456
    long i = (long)bx * blockDim.x + tid;
    const long stride = (long)XBLKS * blockDim.x;
    for (; i < n8; i += stride) {
      const float4* p = (const float4*)(x + i * 8);
      float4 a = p[0];
      float4 b = p[1];
      bf16x8 v;
      v[0] = (bf16)a.x; v[1] = (bf16)a.y; v[2] = (bf16)a.z; v[3] = (bf16)a.w;
      v[4] = (bf16)b.x; v[5] = (bf16)b.y; v[6] = (bf16)b.z; v[7] = (bf16)b.w;
      *(bf16x8*)(xb + i * 8) = v;
    }
  } else {
    // -------- w part: 32x32 tile transpose --------
    const int q   = bx - XBLKS;
    const int org = q / ((OUT_/32) * (D_/32));
    const int rem = q % ((OUT_/32) * (D_/32));
    const int d0  = (rem / (OUT_/32)) * 32;
    const int n0  = (rem % (OUT_/32)) * 32;
    const int tx = tid & 31, ty = tid >> 5;   // 32 x 8
    const float* wsrc = w + (size_t)org * D_ * OUT_;
    bf16* wdst = wt + (size_t)org * OUT_ * D_;
#pragma unroll
    for (int j = 0; j < 32; j += 8)
      tile[ty + j][tx] = wsrc[(size_t)(d0 + ty + j) * OUT_ + (n0 + tx)];
    __syncthreads();
#pragma unroll
    for (int j = 0; j < 32; j += 8)
      wdst[(size_t)(n0 + ty + j) * D_ + (d0 + tx)] = (bf16)tile[tx][ty + j];
  }
}

// ----- 256x256 8-phase bf16 MFMA GEMM, 32x32x16, ONE barrier per phase ------
// A = xb[batch] : [S][D] row-major;  B = wt[org] : [OUT][D] row-major (B^T)
// C[m][n] = sum_k A[m][k]*B[n][k]  + bias[n]
// vs round 7: the pre-MFMA SBAR+lgkmcnt(0) is removed; compiler-inserted
// fine-grained lgkmcnt overlaps ds_reads with the MFMA cluster. A trailing
// lgkmcnt(0) before each end-of-phase barrier preserves the WAR guarantee
// (no wave crosses the barrier with buffer reads in flight). Counted-vmcnt
// checkpoints and staging ledger unchanged (verified rounds 2-7).
__global__ __launch_bounds__(512, 2)
void k_gemm256(const bf16* __restrict__ xb, const bf16* __restrict__ wt,
               const int* __restrict__ oidx, const float* __restrict__ bias,
               float* __restrict__ out) {
  __shared__ __align__(16) char smem[131072];   // A: 2x32KB, B: 2x32KB
  char* const ldsA = smem;
  char* const ldsB = smem + 65536;

  const int batch = blockIdx.y;
  const int bx = blockIdx.x;
  // T1: XCD-aware swizzle (128 tiles, 8 XCDs). XCD = bx&7 owns one tn column.
  const int swz = (bx & 7) * 16 + (bx >> 3);
  const int tn = swz >> 4, tm = swz & 15;
  const int m0 = tm * 256, n0 = tn * 256;
  const int org = oidx[batch];

  const bf16* Ag = xb + (size_t)batch * S_ * D_ + (size_t)m0 * D_;
  const bf16* Bg = wt + (size_t)org * OUT_ * D_ + (size_t)n0 * D_;

  const int tid  = threadIdx.x;
  const int lane = tid & 63, wv = tid >> 6;
  const int wr = wv >> 2, wc = wv & 3;        // 2x4 wave grid, per-wave 128x64 out
  const int l31 = lane & 31, hi = lane >> 5;

  // Read-side swizzle key(r) = (r&7)^((r>>3)&3) (verified conflict-free r5).
  const int xorv = ((lane & 7) ^ ((lane >> 3) & 3)) << 4;
  const int off[4] = { (0  + hi * 16) ^ xorv, (32 + hi * 16) ^ xorv,
                       (64 + hi * 16) ^ xorv, (96 + hi * 16) ^ xorv };
  const int arow = (wr * 128 + l31) * 128;    // + mt*4096
  const int brow = (wc * 64  + l31) * 128;    // + nt*4096

  // Stage-side: linear LDS dest + inverse-swizzled per-lane GLOBAL source.
  const int srow = tid >> 3;
  const int scol = (((tid & 7) ^ ((tid >> 3) & 7) ^ ((tid >> 6) & 3))) << 3;
  const int soff = wv * 1024;

#define LDA(v, mt, ks) (*(const bf16x8*)(ldsA + (v)*32768 + arow + (mt)*4096 + off[ks]))
#define LDB(v, nt, ks) (*(const bf16x8*)(ldsB + (v)*32768 + brow + (nt)*4096 + off[ks]))

#define STAGE_HALF(gptr, ldsbase, h, kb) do {                                            \
    __builtin_amdgcn_global_load_lds(                                                    \
      (__attribute__((address_space(1))) void*)((gptr) + (size_t)((h)*128 + srow) * D_ + (kb) + scol), \
      (__attribute__((address_space(3))) void*)((ldsbase) + (h)*16384 + soff), 16, 0, 0);\
    __builtin_amdgcn_global_load_lds(                                                    \
      (__attribute__((address_space(1))) void*)((gptr) + (size_t)((h)*128 + 64 + srow) * D_ + (kb) + scol), \
      (__attribute__((address_space(3))) void*)((ldsbase) + (h)*16384 + 8192 + soff), 16, 0, 0); \
  } while (0)

#define SBAR()  __builtin_amdgcn_s_barrier()
#define LGK0()  asm volatile("s_waitcnt lgkmcnt(0)" ::: "memory")
#define VMC4()  asm volatile("s_waitcnt vmcnt(4)" ::: "memory")
#define VMC0()  asm volatile("s_waitcnt vmcnt(0)" ::: "memory")
#define PRIO(p) __builtin_amdgcn_s_setprio(p)

  bf16x8 a[2][4], b0[4], b1[4];
  f32x16 acc[4][2];
#pragma unroll
  for (int mt = 0; mt < 4; ++mt)
#pragma unroll
    for (int nt = 0; nt < 2; ++nt)
#pragma unroll
      for (int rr = 0; rr < 16; ++rr) acc[mt][nt][rr] = 0.f;

#define READ_A2(v, mbase) do { _Pragma("unroll") for (int mm = 0; mm < 2; ++mm) \
    _Pragma("unroll") for (int ks = 0; ks < 4; ++ks) \
      a[mm][ks] = LDA(v, (mbase) + mm, ks); } while (0)
#define READ_B4(v, nt, bb) do { _Pragma("unroll") for (int ks = 0; ks < 4; ++ks) \
      bb[ks] = LDB(v, nt, ks); } while (0)
#define MFMA_O(mbase, nt, bb) do { \
    _Pragma("unroll") for (int mm = 0; mm < 2; ++mm) \
    _Pragma("unroll") for (int ks = 0; ks < 4; ++ks) \
      acc[(mbase)+mm][nt] = __builtin_amdgcn_mfma_f32_32x32x16_bf16( \
          a[mm][ks], bb[ks], acc[(mbase)+mm][nt], 0, 0, 0); } while (0)

  // ---- prologue: tile0 B+A, tile1 B (6 halves = 12 loads); newest 2 halves
  // (tile1 B) may stay outstanding at the barrier.
  STAGE_HALF(Bg, ldsB, 0, 0);
  STAGE_HALF(Bg, ldsB, 1, 0);
  STAGE_HALF(Ag, ldsA, 0, 0);
  STAGE_HALF(Ag, ldsA, 1, 0);
  STAGE_HALF(Bg, ldsB + 32768, 0, BK64);
  STAGE_HALF(Bg, ldsB + 32768, 1, BK64);
  VMC4();
  SBAR();

  for (int i = 0; i < NKT / 2; ++i) {
    const int k1 = (2 * i + 1) * BK64;
    int t2 = 2 * i + 2; if (t2 > NKT - 1) t2 = NKT - 1;   // clamp, never skip:
    int t3 = 2 * i + 3; if (t3 > NKT - 1) t3 = NKT - 1;   // keeps vmcnt math exact
    const int k2 = t2 * BK64, k3 = t3 * BK64;

    // P1: tile 2i, quad(mt0-1 x nt0); stage A-half0(2i+1) -> buf1
    READ_A2(0, 0); READ_B4(0, 0, b0);
    STAGE_HALF(Ag, ldsA + 32768, 0, k1);
    PRIO(1); MFMA_O(0, 0, b0); PRIO(0);
    LGK0(); SBAR();
    // P2: quad(mt0-1 x nt1); stage A-half1(2i+1) -> buf1
    READ_B4(0, 1, b1);
    STAGE_HALF(Ag, ldsA + 32768, 1, k1);
    PRIO(1); MFMA_O(0, 1, b1); PRIO(0);
    LGK0(); SBAR();
    // P3: quad(mt2-3 x nt0); stage B-half0(2i+2) -> buf0
    READ_A2(0, 2);
    STAGE_HALF(Bg, ldsB, 0, k2);
    PRIO(1); MFMA_O(2, 0, b0); PRIO(0);
    LGK0(); SBAR();
    // P4: quad(mt2-3 x nt1); stage B-half1(2i+2); checkpoint vmcnt(4)
    STAGE_HALF(Bg, ldsB, 1, k2);
    PRIO(1); MFMA_O(2, 1, b1); PRIO(0);
    VMC4();
    SBAR();
    // P5: tile 2i+1, quad(mt0-1 x nt0); stage A-half0(2i+2) -> buf0
    READ_A2(1, 0); READ_B4(1, 0, b0);
    STAGE_HALF(Ag, ldsA, 0, k2);
    PRIO(1); MFMA_O(0, 0, b0); PRIO(0);
    LGK0(); SBAR();
    // P6: quad(mt0-1 x nt1); stage A-half1(2i+2) -> buf0
    READ_B4(1, 1, b1);
    STAGE_HALF(Ag, ldsA, 1, k2);
    PRIO(1); MFMA_O(0, 1, b1); PRIO(0);
    LGK0(); SBAR();
    // P7: quad(mt2-3 x nt0); stage B-half0(2i+3) -> buf1
    READ_A2(1, 2);
    STAGE_HALF(Bg, ldsB + 32768, 0, k3);
    PRIO(1); MFMA_O(2, 0, b0); PRIO(0);
    LGK0(); SBAR();
    // P8: quad(mt2-3 x nt1); stage B-half1(2i+3); checkpoint vmcnt(4)
    STAGE_HALF(Bg, ldsB + 32768, 1, k3);
    PRIO(1); MFMA_O(2, 1, b1); PRIO(0);
    VMC4();
    SBAR();
  }

  VMC0();  // drain trailing (clamped) stages before stores

  // epilogue: 32x32 C/D layout col = lane&31, row = (reg&3)+8*(reg>>2)+4*(lane>>5)
  float* Og = out + (size_t)batch * S_ * OUT_ + (size_t)m0 * OUT_ + n0;
  const float* bbase = bias + (size_t)org * OUT_ + n0;
#pragma unroll
  for (int nt = 0; nt < 2; ++nt) {
    const int col = wc * 64 + nt * 32 + l31;
    const float bv = bbase[col];
#pragma unroll
    for (int mt = 0; mt < 4; ++mt) {
#pragma unroll
      for (int rr = 0; rr < 16; ++rr) {
        const int row = wr * 128 + mt * 32 + 4 * hi + (rr & 3) + 8 * (rr >> 2);
        Og[(size_t)row * OUT_ + col] = acc[mt][nt][rr] + bv;
      }
    }
  }
#undef LDA
#undef LDB
#undef STAGE_HALF
#undef SBAR
#undef LGK0
#undef VMC4
#undef VMC0
#undef PRIO
#undef READ_A2
#undef READ_B4
#undef MFMA_O
}

// ---------------- fallback: naive fp32 (only if ws too small) ---------------
__global__ void k_gemm_fallback(const float* __restrict__ x, const int* __restrict__ oidx,
                                const float* __restrict__ w, const float* __restrict__ bias,
                                float* __restrict__ out) {
  const int b = blockIdx.z;
  const int org = oidx[b];
  const int n = blockIdx.x * 64 + threadIdx.x;
  const int m = blockIdx.y * 4 + threadIdx.y;
  const float* xr = x + ((size_t)b * S_ + m) * D_;
  const float* wp = w + (size_t)org * D_ * OUT_ + n;
  float acc = 0.f;
  for (int k = 0; k < D_; ++k) acc += xr[k] * wp[(size_t)k * OUT_];
  out[((size_t)b * S_ + m) * OUT_ + n] = acc + bias[(size_t)org * OUT_ + n];
}

extern "C" void kernel_launch(void* const* d_in, const int* in_sizes, int n_in,
                              void* d_out, int out_size, void* d_ws, size_t ws_size,
                              hipStream_t stream) {
  const float* x    = (const float*)d_in[0];
  const int*   oidx = (const int*)d_in[1];
  const float* w    = (const float*)d_in[2];
  const float* bias = (const float*)d_in[3];
  float* out = (float*)d_out;

  const size_t xb_elems = (size_t)B_ * S_ * D_;      // 50,331,648
  const size_t wt_elems = (size_t)ORG_ * OUT_ * D_;  // 12,582,912
  const size_t need = (xb_elems + wt_elems) * sizeof(bf16);  // ~126 MB

  if (ws_size < need) {
    dim3 g(OUT_ / 64, S_ / 4, B_);
    k_gemm_fallback<<<g, dim3(64, 4), 0, stream>>>(x, oidx, w, bias, out);
    return;
  }

  bf16* xb = (bf16*)d_ws;
  bf16* wt = xb + xb_elems;

  k_cvt_all<<<XBLKS + WTBLK, 256, 0, stream>>>(x, xb, w, wt);
  dim3 gg(128, B_);
  k_gemm256<<<gg, 512, 0, stream>>>(xb, wt, oidx, bias, out);
}

// Round 9
// 294.074 us; speedup vs baseline: 1.4625x; 1.0069x over previous
//
#include <hip/hip_runtime.h>
#include <hip/hip_bf16.h>
#include <stdint.h>

#define B_    8
#define S_    4096
#define D_    1536
#define ORG_  4
#define OUT_  2048

typedef __bf16 bf16;
typedef __attribute__((ext_vector_type(8)))  bf16  bf16x8;
typedef __attribute__((ext_vector_type(16))) float f32x16;

#define BK64 64
#define NKT  (D_ / BK64)   // 24 K-tiles

#define XBLKS 2048                       // blocks doing the x-stream part
#define WTBLK (ORG_ * (OUT_/32) * (D_/32))  // 12288 blocks doing w-transpose

// ---- merged convert: x f32->bf16 stream  +  w f32 [O][D][OUT] -> bf16 [O][OUT][D]
__global__ void k_cvt_all(const float* __restrict__ x, bf16* __restrict__ xb,
                          const float* __restrict__ w, bf16* __restrict__ wt) {
  __shared__ float tile[32][33];
  const int bx = blockIdx.x;
  const int tid = threadIdx.x;

  if (bx < XBLKS) {
    // -------- x part: 8 elems/thread/iter, grid-stride --------
    const long n8 = (long)B_ * S_ * D_ / 8;   // 6,291,456
    long i = (long)bx * blockDim.x + tid;
    const long stride = (long)XBLKS * blockDim.x;
    for (; i < n8; i += stride) {
      const float4* p = (const float4*)(x + i * 8);
      float4 a = p[0];
      float4 b = p[1];
      bf16x8 v;
      v[0] = (bf16)a.x; v[1] = (bf16)a.y; v[2] = (bf16)a.z; v[3] = (bf16)a.w;
      v[4] = (bf16)b.x; v[5] = (bf16)b.y; v[6] = (bf16)b.z; v[7] = (bf16)b.w;
      *(bf16x8*)(xb + i * 8) = v;
    }
  } else {
    // -------- w part: 32x32 tile transpose --------
    const int q   = bx - XBLKS;
    const int org = q / ((OUT_/32) * (D_/32));
    const int rem = q % ((OUT_/32) * (D_/32));
    const int d0  = (rem / (OUT_/32)) * 32;
    const int n0  = (rem % (OUT_/32)) * 32;
    const int tx = tid & 31, ty = tid >> 5;   // 32 x 8
    const float* wsrc = w + (size_t)org * D_ * OUT_;
    bf16* wdst = wt + (size_t)org * OUT_ * D_;
#pragma unroll
    for (int j = 0; j < 32; j += 8)
      tile[ty + j][tx] = wsrc[(size_t)(d0 + ty + j) * OUT_ + (n0 + tx)];
    __syncthreads();
#pragma unroll
    for (int j = 0; j < 32; j += 8)
      wdst[(size_t)(n0 + ty + j) * D_ + (d0 + tx)] = (bf16)tile[tx][ty + j];
  }
}

// ----- 256x256 8-phase bf16 MFMA GEMM, 32x32x16, deep prefetch vmcnt(6) -----
// A = xb[batch] : [S][D] row-major;  B = wt[org] : [OUT][D] row-major (B^T)
// C[m][n] = sum_k A[m][k]*B[n][k]  + bias[n]
// vs round 8: staging issue moved one phase earlier where WAR allows
// (A-buf fully read after P3/P7; B-buf after P2/P6), giving 3 half-tiles in
// flight and >=4 phases of latency coverage per load; checkpoints vmcnt(6)
// (= m201 template formula: 2 loads/half x 3 halves in flight).
// Ledger at P4-end (oldest first): B(t1)h1[P8prev] A(t1)h0[P8prev] A(t1)h1[P1]
//   B(t2)h0[P3] B(t2)h1+A(t2)h0[P4] = 10 outstanding; allow newest 6.
// Ledger at P8-end: A(t2)h0[P4] A(t2)h1[P5] B(t3)h0[P7] B(t3)h1+A(t3)h0[P8]
//   = 10; allow newest 6. One barrier per phase (round-8 verified).
__global__ __launch_bounds__(512, 2)
void k_gemm256(const bf16* __restrict__ xb, const bf16* __restrict__ wt,
               const int* __restrict__ oidx, const float* __restrict__ bias,
               float* __restrict__ out) {
  __shared__ __align__(16) char smem[131072];   // A: 2x32KB, B: 2x32KB
  char* const ldsA = smem;
  char* const ldsB = smem + 65536;

  const int batch = blockIdx.y;
  const int bx = blockIdx.x;
  // T1: XCD-aware swizzle (128 tiles, 8 XCDs). XCD = bx&7 owns one tn column.
  const int swz = (bx & 7) * 16 + (bx >> 3);
  const int tn = swz >> 4, tm = swz & 15;
  const int m0 = tm * 256, n0 = tn * 256;
  const int org = oidx[batch];

  const bf16* Ag = xb + (size_t)batch * S_ * D_ + (size_t)m0 * D_;
  const bf16* Bg = wt + (size_t)org * OUT_ * D_ + (size_t)n0 * D_;

  const int tid  = threadIdx.x;
  const int lane = tid & 63, wv = tid >> 6;
  const int wr = wv >> 2, wc = wv & 3;        // 2x4 wave grid, per-wave 128x64 out
  const int l31 = lane & 31, hi = lane >> 5;

  // Read-side swizzle key(r) = (r&7)^((r>>3)&3) (verified conflict-free r5).
  const int xorv = ((lane & 7) ^ ((lane >> 3) & 3)) << 4;
  const int off[4] = { (0  + hi * 16) ^ xorv, (32 + hi * 16) ^ xorv,
                       (64 + hi * 16) ^ xorv, (96 + hi * 16) ^ xorv };
  const int arow = (wr * 128 + l31) * 128;    // + mt*4096
  const int brow = (wc * 64  + l31) * 128;    // + nt*4096

  // Stage-side: linear LDS dest + inverse-swizzled per-lane GLOBAL source.
  const int srow = tid >> 3;
  const int scol = (((tid & 7) ^ ((tid >> 3) & 7) ^ ((tid >> 6) & 3))) << 3;
  const int soff = wv * 1024;

#define LDA(v, mt, ks) (*(const bf16x8*)(ldsA + (v)*32768 + arow + (mt)*4096 + off[ks]))
#define LDB(v, nt, ks) (*(const bf16x8*)(ldsB + (v)*32768 + brow + (nt)*4096 + off[ks]))

#define STAGE_HALF(gptr, ldsbase, h, kb) do {                                            \
    __builtin_amdgcn_global_load_lds(                                                    \
      (__attribute__((address_space(1))) void*)((gptr) + (size_t)((h)*128 + srow) * D_ + (kb) + scol), \
      (__attribute__((address_space(3))) void*)((ldsbase) + (h)*16384 + soff), 16, 0, 0);\
    __builtin_amdgcn_global_load_lds(                                                    \
      (__attribute__((address_space(1))) void*)((gptr) + (size_t)((h)*128 + 64 + srow) * D_ + (kb) + scol), \
      (__attribute__((address_space(3))) void*)((ldsbase) + (h)*16384 + 8192 + soff), 16, 0, 0); \
  } while (0)

#define SBAR()  __builtin_amdgcn_s_barrier()
#define LGK0()  asm volatile("s_waitcnt lgkmcnt(0)" ::: "memory")
#define VMC6()  asm volatile("s_waitcnt vmcnt(6)" ::: "memory")
#define VMC0()  asm volatile("s_waitcnt vmcnt(0)" ::: "memory")
#define PRIO(p) __builtin_amdgcn_s_setprio(p)

  bf16x8 a[2][4], b0[4], b1[4];
  f32x16 acc[4][2];
#pragma unroll
  for (int mt = 0; mt < 4; ++mt)
#pragma unroll
    for (int nt = 0; nt < 2; ++nt)
#pragma unroll
      for (int rr = 0; rr < 16; ++rr) acc[mt][nt][rr] = 0.f;

#define READ_A2(v, mbase) do { _Pragma("unroll") for (int mm = 0; mm < 2; ++mm) \
    _Pragma("unroll") for (int ks = 0; ks < 4; ++ks) \
      a[mm][ks] = LDA(v, (mbase) + mm, ks); } while (0)
#define READ_B4(v, nt, bb) do { _Pragma("unroll") for (int ks = 0; ks < 4; ++ks) \
      bb[ks] = LDB(v, nt, ks); } while (0)
#define MFMA_O(mbase, nt, bb) do { \
    _Pragma("unroll") for (int mm = 0; mm < 2; ++mm) \
    _Pragma("unroll") for (int ks = 0; ks < 4; ++ks) \
      acc[(mbase)+mm][nt] = __builtin_amdgcn_mfma_f32_32x32x16_bf16( \
          a[mm][ks], bb[ks], acc[(mbase)+mm][nt], 0, 0, 0); } while (0)

  // ---- prologue: B(0), A(0), B(1), A(1)h0 = 14 loads; wait oldest 8
  // (B(0)+A(0)) with vmcnt(6) = B(1) 4 + A(1)h0 2 outstanding.
  STAGE_HALF(Bg, ldsB, 0, 0);
  STAGE_HALF(Bg, ldsB, 1, 0);
  STAGE_HALF(Ag, ldsA, 0, 0);
  STAGE_HALF(Ag, ldsA, 1, 0);
  STAGE_HALF(Bg, ldsB + 32768, 0, BK64);
  STAGE_HALF(Bg, ldsB + 32768, 1, BK64);
  STAGE_HALF(Ag, ldsA + 32768, 0, BK64);
  VMC6();
  SBAR();

  for (int i = 0; i < NKT / 2; ++i) {
    const int k1 = (2 * i + 1) * BK64;
    int t2 = 2 * i + 2; if (t2 > NKT - 1) t2 = NKT - 1;   // clamp, never skip:
    int t3 = 2 * i + 3; if (t3 > NKT - 1) t3 = NKT - 1;   // keeps vmcnt math exact
    const int k2 = t2 * BK64, k3 = t3 * BK64;

    // P1: tile 2i, quad(mt0-1 x nt0); stage A(t1)h1 -> buf1 (h0 staged P8prev)
    READ_A2(0, 0); READ_B4(0, 0, b0);
    STAGE_HALF(Ag, ldsA + 32768, 1, k1);
    PRIO(1); MFMA_O(0, 0, b0); PRIO(0);
    LGK0(); SBAR();
    // P2: quad(mt0-1 x nt1); no stage
    READ_B4(0, 1, b1);
    PRIO(1); MFMA_O(0, 1, b1); PRIO(0);
    LGK0(); SBAR();
    // P3: quad(mt2-3 x nt0); stage B(t2)h0 -> buf0 (Bbuf0 read done after P2)
    READ_A2(0, 2);
    STAGE_HALF(Bg, ldsB, 0, k2);
    PRIO(1); MFMA_O(2, 0, b0); PRIO(0);
    LGK0(); SBAR();
    // P4: quad(mt2-3 x nt1); stage B(t2)h1 + A(t2)h0 (Abuf0 read done after
    // P3); checkpoint vmcnt(6) -> A(t1)+B(t1) complete for P5.
    STAGE_HALF(Bg, ldsB, 1, k2);
    STAGE_HALF(Ag, ldsA, 0, k2);
    PRIO(1); MFMA_O(2, 1, b1); PRIO(0);
    VMC6();
    SBAR();
    // P5: tile 2i+1, quad(mt0-1 x nt0); stage A(t2)h1 -> buf0
    READ_A2(1, 0); READ_B4(1, 0, b0);
    STAGE_HALF(Ag, ldsA, 1, k2);
    PRIO(1); MFMA_O(0, 0, b0); PRIO(0);
    LGK0(); SBAR();
    // P6: quad(mt0-1 x nt1); no stage
    READ_B4(1, 1, b1);
    PRIO(1); MFMA_O(0, 1, b1); PRIO(0);
    LGK0(); SBAR();
    // P7: quad(mt2-3 x nt0); stage B(t3)h0 -> buf1 (Bbuf1 read done after P6)
    READ_A2(1, 2);
    STAGE_HALF(Bg, ldsB + 32768, 0, k3);
    PRIO(1); MFMA_O(2, 0, b0); PRIO(0);
    LGK0(); SBAR();
    // P8: quad(mt2-3 x nt1); stage B(t3)h1 + A(t3)h0 -> buf1 (Abuf1 read done
    // after P7); checkpoint vmcnt(6) -> A(t2)+B(t2) complete for next P1.
    STAGE_HALF(Bg, ldsB + 32768, 1, k3);
    STAGE_HALF(Ag, ldsA + 32768, 0, k3);
    PRIO(1); MFMA_O(2, 1, b1); PRIO(0);
    VMC6();
    SBAR();
  }

  VMC0();  // drain trailing (clamped) stages before stores

  // epilogue: 32x32 C/D layout col = lane&31, row = (reg&3)+8*(reg>>2)+4*(lane>>5)
  float* Og = out + (size_t)batch * S_ * OUT_ + (size_t)m0 * OUT_ + n0;
  const float* bbase = bias + (size_t)org * OUT_ + n0;
#pragma unroll
  for (int nt = 0; nt < 2; ++nt) {
    const int col = wc * 64 + nt * 32 + l31;
    const float bv = bbase[col];
#pragma unroll
    for (int mt = 0; mt < 4; ++mt) {
#pragma unroll
      for (int rr = 0; rr < 16; ++rr) {
        const int row = wr * 128 + mt * 32 + 4 * hi + (rr & 3) + 8 * (rr >> 2);
        Og[(size_t)row * OUT_ + col] = acc[mt][nt][rr] + bv;
      }
    }
  }
#undef LDA
#undef LDB
#undef STAGE_HALF
#undef SBAR
#undef LGK0
#undef VMC6
#undef VMC0
#undef PRIO
#undef READ_A2
#undef READ_B4
#undef MFMA_O
}

// ---------------- fallback: naive fp32 (only if ws too small) ---------------
__global__ void k_gemm_fallback(const float* __restrict__ x, const int* __restrict__ oidx,
                                const float* __restrict__ w, const float* __restrict__ bias,
                                float* __restrict__ out) {
  const int b = blockIdx.z;
  const int org = oidx[b];
  const int n = blockIdx.x * 64 + threadIdx.x;
  const int m = blockIdx.y * 4 + threadIdx.y;
  const float* xr = x + ((size_t)b * S_ + m) * D_;
  const float* wp = w + (size_t)org * D_ * OUT_ + n;
  float acc = 0.f;
  for (int k = 0; k < D_; ++k) acc += xr[k] * wp[(size_t)k * OUT_];
  out[((size_t)b * S_ + m) * OUT_ + n] = acc + bias[(size_t)org * OUT_ + n];
}

extern "C" void kernel_launch(void* const* d_in, const int* in_sizes, int n_in,
                              void* d_out, int out_size, void* d_ws, size_t ws_size,
                              hipStream_t stream) {
  const float* x    = (const float*)d_in[0];
  const int*   oidx = (const int*)d_in[1];
  const float* w    = (const float*)d_in[2];
  const float* bias = (const float*)d_in[3];
  float* out = (float*)d_out;

  const size_t xb_elems = (size_t)B_ * S_ * D_;      // 50,331,648
  const size_t wt_elems = (size_t)ORG_ * OUT_ * D_;  // 12,582,912
  const size_t need = (xb_elems + wt_elems) * sizeof(bf16);  // ~126 MB

  if (ws_size < need) {
    dim3 g(OUT_ / 64, S_ / 4, B_);
    k_gemm_fallback<<<g, dim3(64, 4), 0, stream>>>(x, oidx, w, bias, out);
    return;
  }

  bf16* xb = (bf16*)d_ws;
  bf16* wt = xb + xb_elems;

  k_cvt_all<<<XBLKS + WTBLK, 256, 0, stream>>>(x, xb, w, wt);
  dim3 gg(128, B_);
  k_gemm256<<<gg, 512, 0, stream>>>(xb, wt, oidx, bias, out);
}

// Round 11
// 272.689 us; speedup vs baseline: 1.5771x; 1.0784x over previous
//
#include <hip/hip_runtime.h>
#include <hip/hip_bf16.h>
#include <stdint.h>

#define B_    8
#define S_    4096
#define D_    1536
#define ORG_  4
#define OUT_  2048

typedef __bf16 bf16;
typedef __attribute__((ext_vector_type(8)))  bf16  bf16x8;
typedef __attribute__((ext_vector_type(4)))  float f32x4n;   // native vec for nt builtins
typedef __attribute__((ext_vector_type(16))) float f32x16;

#define BK64 64
#define NKT  (D_ / BK64)   // 24 K-tiles

#define XBLKS 2048                       // blocks doing the x-stream part
#define WTBLK (ORG_ * (OUT_/32) * (D_/32))  // 12288 blocks doing w-transpose

// ---- merged convert: x f32->bf16 stream  +  w f32 [O][D][OUT] -> bf16 [O][OUT][D]
// x and w are read-once -> nontemporal loads (don't evict the xb/wt we are
// writing, which the GEMM re-reads from L3).
__global__ void k_cvt_all(const float* __restrict__ x, bf16* __restrict__ xb,
                          const float* __restrict__ w, bf16* __restrict__ wt) {
  __shared__ float tile[32][33];
  const int bx = blockIdx.x;
  const int tid = threadIdx.x;

  if (bx < XBLKS) {
    // -------- x part: 8 elems/thread/iter, grid-stride --------
    const long n8 = (long)B_ * S_ * D_ / 8;   // 6,291,456
    long i = (long)bx * blockDim.x + tid;
    const long stride = (long)XBLKS * blockDim.x;
    for (; i < n8; i += stride) {
      const f32x4n* p = (const f32x4n*)(x + i * 8);
      f32x4n a = __builtin_nontemporal_load(p);
      f32x4n b = __builtin_nontemporal_load(p + 1);
      bf16x8 v;
      v[0] = (bf16)a[0]; v[1] = (bf16)a[1]; v[2] = (bf16)a[2]; v[3] = (bf16)a[3];
      v[4] = (bf16)b[0]; v[5] = (bf16)b[1]; v[6] = (bf16)b[2]; v[7] = (bf16)b[3];
      *(bf16x8*)(xb + i * 8) = v;
    }
  } else {
    // -------- w part: 32x32 tile transpose --------
    const int q   = bx - XBLKS;
    const int org = q / ((OUT_/32) * (D_/32));
    const int rem = q % ((OUT_/32) * (D_/32));
    const int d0  = (rem / (OUT_/32)) * 32;
    const int n0  = (rem % (OUT_/32)) * 32;
    const int tx = tid & 31, ty = tid >> 5;   // 32 x 8
    const float* wsrc = w + (size_t)org * D_ * OUT_;
    bf16* wdst = wt + (size_t)org * OUT_ * D_;
#pragma unroll
    for (int j = 0; j < 32; j += 8)
      tile[ty + j][tx] = __builtin_nontemporal_load(
          wsrc + (size_t)(d0 + ty + j) * OUT_ + (n0 + tx));
    __syncthreads();
#pragma unroll
    for (int j = 0; j < 32; j += 8)
      wdst[(size_t)(n0 + ty + j) * D_ + (d0 + tx)] = (bf16)tile[tx][ty + j];
  }
}

// ----- 256x256 8-phase bf16 MFMA GEMM, 32x32x16, ONE barrier per phase ------
// A = xb[batch] : [S][D] row-major;  B = wt[org] : [OUT][D] row-major (B^T)
// C[m][n] = sum_k A[m][k]*B[n][k]  + bias[n]
// Schedule = round-8 verified best (one barrier/phase, vmcnt(4) checkpoints).
// NEW: output stores are nontemporal so the 266MB C-stream does not evict
// xb/wt from L3 (round-9 counters: FETCH 414MB vs 130MB working set).
__global__ __launch_bounds__(512, 2)
void k_gemm256(const bf16* __restrict__ xb, const bf16* __restrict__ wt,
               const int* __restrict__ oidx, const float* __restrict__ bias,
               float* __restrict__ out) {
  __shared__ __align__(16) char smem[131072];   // A: 2x32KB, B: 2x32KB
  char* const ldsA = smem;
  char* const ldsB = smem + 65536;

  const int batch = blockIdx.y;
  const int bx = blockIdx.x;
  // T1: XCD-aware swizzle (128 tiles, 8 XCDs). XCD = bx&7 owns one tn column.
  const int swz = (bx & 7) * 16 + (bx >> 3);
  const int tn = swz >> 4, tm = swz & 15;
  const int m0 = tm * 256, n0 = tn * 256;
  const int org = oidx[batch];

  const bf16* Ag = xb + (size_t)batch * S_ * D_ + (size_t)m0 * D_;
  const bf16* Bg = wt + (size_t)org * OUT_ * D_ + (size_t)n0 * D_;

  const int tid  = threadIdx.x;
  const int lane = tid & 63, wv = tid >> 6;
  const int wr = wv >> 2, wc = wv & 3;        // 2x4 wave grid, per-wave 128x64 out
  const int l31 = lane & 31, hi = lane >> 5;

  // Read-side swizzle key(r) = (r&7)^((r>>3)&3) (verified conflict-free r5).
  const int xorv = ((lane & 7) ^ ((lane >> 3) & 3)) << 4;
  const int off[4] = { (0  + hi * 16) ^ xorv, (32 + hi * 16) ^ xorv,
                       (64 + hi * 16) ^ xorv, (96 + hi * 16) ^ xorv };
  const int arow = (wr * 128 + l31) * 128;    // + mt*4096
  const int brow = (wc * 64  + l31) * 128;    // + nt*4096

  // Stage-side: linear LDS dest + inverse-swizzled per-lane GLOBAL source.
  const int srow = tid >> 3;
  const int scol = (((tid & 7) ^ ((tid >> 3) & 7) ^ ((tid >> 6) & 3))) << 3;
  const int soff = wv * 1024;

#define LDA(v, mt, ks) (*(const bf16x8*)(ldsA + (v)*32768 + arow + (mt)*4096 + off[ks]))
#define LDB(v, nt, ks) (*(const bf16x8*)(ldsB + (v)*32768 + brow + (nt)*4096 + off[ks]))

#define STAGE_HALF(gptr, ldsbase, h, kb) do {                                            \
    __builtin_amdgcn_global_load_lds(                                                    \
      (__attribute__((address_space(1))) void*)((gptr) + (size_t)((h)*128 + srow) * D_ + (kb) + scol), \
      (__attribute__((address_space(3))) void*)((ldsbase) + (h)*16384 + soff), 16, 0, 0);\
    __builtin_amdgcn_global_load_lds(                                                    \
      (__attribute__((address_space(1))) void*)((gptr) + (size_t)((h)*128 + 64 + srow) * D_ + (kb) + scol), \
      (__attribute__((address_space(3))) void*)((ldsbase) + (h)*16384 + 8192 + soff), 16, 0, 0); \
  } while (0)

#define SBAR()  __builtin_amdgcn_s_barrier()
#define LGK0()  asm volatile("s_waitcnt lgkmcnt(0)" ::: "memory")
#define VMC4()  asm volatile("s_waitcnt vmcnt(4)" ::: "memory")
#define VMC0()  asm volatile("s_waitcnt vmcnt(0)" ::: "memory")
#define PRIO(p) __builtin_amdgcn_s_setprio(p)

  bf16x8 a[2][4], b0[4], b1[4];
  f32x16 acc[4][2];
#pragma unroll
  for (int mt = 0; mt < 4; ++mt)
#pragma unroll
    for (int nt = 0; nt < 2; ++nt)
#pragma unroll
      for (int rr = 0; rr < 16; ++rr) acc[mt][nt][rr] = 0.f;

#define READ_A2(v, mbase) do { _Pragma("unroll") for (int mm = 0; mm < 2; ++mm) \
    _Pragma("unroll") for (int ks = 0; ks < 4; ++ks) \
      a[mm][ks] = LDA(v, (mbase) + mm, ks); } while (0)
#define READ_B4(v, nt, bb) do { _Pragma("unroll") for (int ks = 0; ks < 4; ++ks) \
      bb[ks] = LDB(v, nt, ks); } while (0)
#define MFMA_O(mbase, nt, bb) do { \
    _Pragma("unroll") for (int mm = 0; mm < 2; ++mm) \
    _Pragma("unroll") for (int ks = 0; ks < 4; ++ks) \
      acc[(mbase)+mm][nt] = __builtin_amdgcn_mfma_f32_32x32x16_bf16( \
          a[mm][ks], bb[ks], acc[(mbase)+mm][nt], 0, 0, 0); } while (0)

  // ---- prologue: tile0 B+A, tile1 B (6 halves = 12 loads); newest 2 halves
  // (tile1 B) may stay outstanding at the barrier.
  STAGE_HALF(Bg, ldsB, 0, 0);
  STAGE_HALF(Bg, ldsB, 1, 0);
  STAGE_HALF(Ag, ldsA, 0, 0);
  STAGE_HALF(Ag, ldsA, 1, 0);
  STAGE_HALF(Bg, ldsB + 32768, 0, BK64);
  STAGE_HALF(Bg, ldsB + 32768, 1, BK64);
  VMC4();
  SBAR();

  for (int i = 0; i < NKT / 2; ++i) {
    const int k1 = (2 * i + 1) * BK64;
    int t2 = 2 * i + 2; if (t2 > NKT - 1) t2 = NKT - 1;   // clamp, never skip:
    int t3 = 2 * i + 3; if (t3 > NKT - 1) t3 = NKT - 1;   // keeps vmcnt math exact
    const int k2 = t2 * BK64, k3 = t3 * BK64;

    // P1: tile 2i, quad(mt0-1 x nt0); stage A-half0(2i+1) -> buf1
    READ_A2(0, 0); READ_B4(0, 0, b0);
    STAGE_HALF(Ag, ldsA + 32768, 0, k1);
    PRIO(1); MFMA_O(0, 0, b0); PRIO(0);
    LGK0(); SBAR();
    // P2: quad(mt0-1 x nt1); stage A-half1(2i+1) -> buf1
    READ_B4(0, 1, b1);
    STAGE_HALF(Ag, ldsA + 32768, 1, k1);
    PRIO(1); MFMA_O(0, 1, b1); PRIO(0);
    LGK0(); SBAR();
    // P3: quad(mt2-3 x nt0); stage B-half0(2i+2) -> buf0
    READ_A2(0, 2);
    STAGE_HALF(Bg, ldsB, 0, k2);
    PRIO(1); MFMA_O(2, 0, b0); PRIO(0);
    LGK0(); SBAR();
    // P4: quad(mt2-3 x nt1); stage B-half1(2i+2); checkpoint vmcnt(4)
    STAGE_HALF(Bg, ldsB, 1, k2);
    PRIO(1); MFMA_O(2, 1, b1); PRIO(0);
    VMC4();
    SBAR();
    // P5: tile 2i+1, quad(mt0-1 x nt0); stage A-half0(2i+2) -> buf0
    READ_A2(1, 0); READ_B4(1, 0, b0);
    STAGE_HALF(Ag, ldsA, 0, k2);
    PRIO(1); MFMA_O(0, 0, b0); PRIO(0);
    LGK0(); SBAR();
    // P6: quad(mt0-1 x nt1); stage A-half1(2i+2) -> buf0
    READ_B4(1, 1, b1);
    STAGE_HALF(Ag, ldsA, 1, k2);
    PRIO(1); MFMA_O(0, 1, b1); PRIO(0);
    LGK0(); SBAR();
    // P7: quad(mt2-3 x nt0); stage B-half0(2i+3) -> buf1
    READ_A2(1, 2);
    STAGE_HALF(Bg, ldsB + 32768, 0, k3);
    PRIO(1); MFMA_O(2, 0, b0); PRIO(0);
    LGK0(); SBAR();
    // P8: quad(mt2-3 x nt1); stage B-half1(2i+3); checkpoint vmcnt(4)
    STAGE_HALF(Bg, ldsB + 32768, 1, k3);
    PRIO(1); MFMA_O(2, 1, b1); PRIO(0);
    VMC4();
    SBAR();
  }

  VMC0();  // drain trailing (clamped) stages before stores

  // epilogue: 32x32 C/D layout col = lane&31, row = (reg&3)+8*(reg>>2)+4*(lane>>5)
  // Nontemporal: C is write-once -> don't let it evict xb/wt from L3.
  float* Og = out + (size_t)batch * S_ * OUT_ + (size_t)m0 * OUT_ + n0;
  const float* bbase = bias + (size_t)org * OUT_ + n0;
#pragma unroll
  for (int nt = 0; nt < 2; ++nt) {
    const int col = wc * 64 + nt * 32 + l31;
    const float bv = bbase[col];
#pragma unroll
    for (int mt = 0; mt < 4; ++mt) {
#pragma unroll
      for (int rr = 0; rr < 16; ++rr) {
        const int row = wr * 128 + mt * 32 + 4 * hi + (rr & 3) + 8 * (rr >> 2);
        __builtin_nontemporal_store(acc[mt][nt][rr] + bv,
                                    &Og[(size_t)row * OUT_ + col]);
      }
    }
  }
#undef LDA
#undef LDB
#undef STAGE_HALF
#undef SBAR
#undef LGK0
#undef VMC4
#undef VMC0
#undef PRIO
#undef READ_A2
#undef READ_B4
#undef MFMA_O
}

// ---------------- fallback: naive fp32 (only if ws too small) ---------------
__global__ void k_gemm_fallback(const float* __restrict__ x, const int* __restrict__ oidx,
                                const float* __restrict__ w, const float* __restrict__ bias,
                                float* __restrict__ out) {
  const int b = blockIdx.z;
  const int org = oidx[b];
  const int n = blockIdx.x * 64 + threadIdx.x;
  const int m = blockIdx.y * 4 + threadIdx.y;
  const float* xr = x + ((size_t)b * S_ + m) * D_;
  const float* wp = w + (size_t)org * D_ * OUT_ + n;
  float acc = 0.f;
  for (int k = 0; k < D_; ++k) acc += xr[k] * wp[(size_t)k * OUT_];
  out[((size_t)b * S_ + m) * OUT_ + n] = acc + bias[(size_t)org * OUT_ + n];
}

extern "C" void kernel_launch(void* const* d_in, const int* in_sizes, int n_in,
                              void* d_out, int out_size, void* d_ws, size_t ws_size,
                              hipStream_t stream) {
  const float* x    = (const float*)d_in[0];
  const int*   oidx = (const int*)d_in[1];
  const float* w    = (const float*)d_in[2];
  const float* bias = (const float*)d_in[3];
  float* out = (float*)d_out;

  const size_t xb_elems = (size_t)B_ * S_ * D_;      // 50,331,648
  const size_t wt_elems = (size_t)ORG_ * OUT_ * D_;  // 12,582,912
  const size_t need = (xb_elems + wt_elems) * sizeof(bf16);  // ~126 MB

  if (ws_size < need) {
    dim3 g(OUT_ / 64, S_ / 4, B_);
    k_gemm_fallback<<<g, dim3(64, 4), 0, stream>>>(x, oidx, w, bias, out);
    return;
  }

  bf16* xb = (bf16*)d_ws;
  bf16* wt = xb + xb_elems;

  k_cvt_all<<<XBLKS + WTBLK, 256, 0, stream>>>(x, xb, w, wt);
  dim3 gg(128, B_);
  k_gemm256<<<gg, 512, 0, stream>>>(xb, wt, oidx, bias, out);
}